// Round 1
// baseline (3475.039 us; speedup 1.0000x reference)
//
#include <hip/hip_runtime.h>
#include <hip/hip_bf16.h>
#include <stdint.h>

// Mixtral MoE MLP: T=8192 tokens, H=2048, I=4096, E=8 experts, top-2.
// Strategy: bf16 MFMA grouped GEMM (gather-GEMM-scatter), fp32 weights
// converted to bf16 on the fly during LDS staging. Workspace ~235 MB.

#define T_ 8192
#define H_ 2048
#define I_ 4096
#define E_ 8
#define NSLOT (T_ * 2)

#define BK 32
#define BKP 40  // padded LDS row (bf16 elems) for VALU-staged B tiles

typedef unsigned short ushort_t;
typedef __attribute__((ext_vector_type(8))) short short8;
typedef __attribute__((ext_vector_type(4))) float f32x4;
typedef __attribute__((ext_vector_type(4))) __bf16 bf16x4;

// ---------------------------------------------------------------- convert
__global__ __launch_bounds__(256) void k_convert(const float* __restrict__ src,
                                                 ushort_t* __restrict__ dst) {
  int idx = blockIdx.x * 256 + threadIdx.x;  // one float4 per thread
  float4 v = ((const float4*)src)[idx];
  bf16x4 b = {(__bf16)v.x, (__bf16)v.y, (__bf16)v.z, (__bf16)v.w};
  ((bf16x4*)dst)[idx] = b;
}

// ---------------------------------------------------------------- router
__global__ __launch_bounds__(256) void k_router(const float* __restrict__ hidden,
                                                const float* __restrict__ rw,
                                                int* __restrict__ topi,
                                                float* __restrict__ topw,
                                                int* __restrict__ counts) {
  int wv = threadIdx.x >> 6, lane = threadIdx.x & 63;
  int t = blockIdx.x * 4 + wv;  // one wave per token
  float acc[E_];
#pragma unroll
  for (int e = 0; e < E_; ++e) acc[e] = 0.f;
  const float* hrow = hidden + (size_t)t * H_;
  for (int j = lane; j < H_; j += 64) {
    float h = hrow[j];
#pragma unroll
    for (int e = 0; e < E_; ++e) acc[e] += h * rw[e * H_ + j];
  }
#pragma unroll
  for (int e = 0; e < E_; ++e) {
    float v = acc[e];
    for (int off = 32; off; off >>= 1) v += __shfl_xor(v, off, 64);
    acc[e] = v;
  }
  if (lane == 0) {
    int i0 = 0;
#pragma unroll
    for (int e = 1; e < E_; ++e)
      if (acc[e] > acc[i0]) i0 = e;
    int i1 = -1;
#pragma unroll
    for (int e = 0; e < E_; ++e) {
      if (e == i0) continue;
      if (i1 < 0 || acc[e] > acc[i1]) i1 = e;
    }
    // softmax -> top2 -> renormalize == softmax over the two top logits
    float w0 = 1.f / (1.f + __expf(acc[i1] - acc[i0]));
    topi[2 * t] = i0;
    topi[2 * t + 1] = i1;
    topw[2 * t] = w0;
    topw[2 * t + 1] = 1.f - w0;
    atomicAdd(&counts[i0], 1);
    atomicAdd(&counts[i1], 1);
  }
}

// ---------------------------------------------------------------- prefix
__global__ void k_prefix(const int* __restrict__ counts, int* __restrict__ offsets) {
  if (threadIdx.x == 0 && blockIdx.x == 0) {
    int s = 0;
    for (int e = 0; e < E_; ++e) {
      offsets[e] = s;
      s += counts[e];
    }
    offsets[E_] = s;
  }
}

// ---------------------------------------------------------------- scatter
__global__ __launch_bounds__(256) void k_scatter(const int* __restrict__ topi,
                                                 const float* __restrict__ topw,
                                                 const int* __restrict__ offsets,
                                                 int* __restrict__ cursors,
                                                 int* __restrict__ bucket_token,
                                                 float* __restrict__ slot_weight,
                                                 int* __restrict__ token_slots) {
  int t = blockIdx.x * 256 + threadIdx.x;
  if (t >= T_) return;
#pragma unroll
  for (int k = 0; k < 2; ++k) {
    int e = topi[2 * t + k];
    int pos = atomicAdd(&cursors[e], 1);
    int slot = offsets[e] + pos;
    bucket_token[slot] = t;
    slot_weight[slot] = topw[2 * t + k];
    token_slots[2 * t + k] = slot;
  }
}

// ------------------------------------------------------- async global->LDS
__device__ __forceinline__ void gld_lds16(const void* g, void* l) {
  __builtin_amdgcn_global_load_lds(
      (const __attribute__((address_space(1))) unsigned int*)g,
      (__attribute__((address_space(3))) unsigned int*)l, 16, 0, 0);
}

// ---------------------------------------------------------------- GEMM1
// act[slot, i] = silu(h . wsg_i) * (h . wsu_i), bf16 out. Grid: (Mtile, I/128, E)
__global__ __launch_bounds__(256, 2) void k_gemm1(
    const ushort_t* __restrict__ hidden_bf, const float* __restrict__ ws,
    const int* __restrict__ bucket_token, const int* __restrict__ offsets,
    ushort_t* __restrict__ act) {
  int e = blockIdx.z;
  int start = offsets[e], end = offsets[e + 1];
  int m0 = start + blockIdx.x * 128;
  if (m0 >= end) return;
  int i0 = blockIdx.y * 128;

  __shared__ ushort_t lA[128 * BK];    // 8 KB, unpadded (global_load_lds)
  __shared__ ushort_t lBg[128 * BKP];  // 10 KB, padded
  __shared__ ushort_t lBu[128 * BKP];  // 10 KB

  int tid = threadIdx.x, lane = tid & 63, wv = tid >> 6;
  int wi = wv >> 1, wj = wv & 1;  // 2x2 wave grid, each wave 64x64
  int q = lane >> 4, r16 = lane & 15;

  // A staging: wave wv covers rows [wv*32, wv*32+32); 2 instrs of 16 rows
  const ushort_t* aptr[2];
  ushort_t* adst[2];
#pragma unroll
  for (int j = 0; j < 2; ++j) {
    int row = wv * 32 + j * 16 + (lane >> 2);
    int slot = m0 + row;
    if (slot > end - 1) slot = end - 1;  // tail clamp (epilogue masks)
    int tok = bucket_token[slot];
    aptr[j] = hidden_bf + (size_t)tok * H_ + (lane & 3) * 8;
    adst[j] = &lA[(wv * 32 + j * 16) * BK];
  }

  // B staging: fp32 -> bf16 cvt, 4 float4 per thread per tile
  const float* bgp[4];
  const float* bup[4];
  int boff[4];
  const float* wsE = ws + (size_t)e * (2 * I_) * (size_t)H_;
#pragma unroll
  for (int p = 0; p < 4; ++p) {
    int idx = p * 256 + tid;
    int row = idx >> 3, c4 = idx & 7;
    bgp[p] = wsE + (size_t)(i0 + row) * H_ + c4 * 4;
    bup[p] = wsE + (size_t)(I_ + i0 + row) * H_ + c4 * 4;
    boff[p] = row * BKP + c4 * 4;
  }

  f32x4 accg[4][4], accu[4][4];
  f32x4 z4 = {0.f, 0.f, 0.f, 0.f};
#pragma unroll
  for (int a = 0; a < 4; ++a)
#pragma unroll
    for (int b = 0; b < 4; ++b) {
      accg[a][b] = z4;
      accu[a][b] = z4;
    }

  for (int k0 = 0; k0 < H_; k0 += BK) {
#pragma unroll
    for (int j = 0; j < 2; ++j) gld_lds16(aptr[j] + k0, adst[j]);
#pragma unroll
    for (int p = 0; p < 4; ++p) {
      float4 g = *(const float4*)(bgp[p] + k0);
      float4 u = *(const float4*)(bup[p] + k0);
      bf16x4 gb = {(__bf16)g.x, (__bf16)g.y, (__bf16)g.z, (__bf16)g.w};
      bf16x4 ub = {(__bf16)u.x, (__bf16)u.y, (__bf16)u.z, (__bf16)u.w};
      *(bf16x4*)&lBg[boff[p]] = gb;
      *(bf16x4*)&lBu[boff[p]] = ub;
    }
    __syncthreads();
    short8 af[4], bg[4], bu2[4];
#pragma unroll
    for (int ti = 0; ti < 4; ++ti)
      af[ti] = *(const short8*)&lA[(wi * 64 + ti * 16 + r16) * BK + q * 8];
#pragma unroll
    for (int tj = 0; tj < 4; ++tj) {
      bg[tj] = *(const short8*)&lBg[(wj * 64 + tj * 16 + r16) * BKP + q * 8];
      bu2[tj] = *(const short8*)&lBu[(wj * 64 + tj * 16 + r16) * BKP + q * 8];
    }
#pragma unroll
    for (int ti = 0; ti < 4; ++ti)
#pragma unroll
      for (int tj = 0; tj < 4; ++tj) {
        accg[ti][tj] = __builtin_amdgcn_mfma_f32_16x16x32_bf16(
            af[ti], bg[tj], accg[ti][tj], 0, 0, 0);
        accu[ti][tj] = __builtin_amdgcn_mfma_f32_16x16x32_bf16(
            af[ti], bu2[tj], accu[ti][tj], 0, 0, 0);
      }
    __syncthreads();
  }

  // epilogue: SiLU(g)*u -> bf16. D layout: col=lane&15, row=q*4+r
#pragma unroll
  for (int ti = 0; ti < 4; ++ti)
#pragma unroll
    for (int tj = 0; tj < 4; ++tj)
#pragma unroll
      for (int r = 0; r < 4; ++r) {
        int mrow = wi * 64 + ti * 16 + q * 4 + r;
        int slot = m0 + mrow;
        if (slot < end) {
          int col = i0 + wj * 64 + tj * 16 + r16;
          float g = accg[ti][tj][r], u = accu[ti][tj][r];
          float a = g / (1.f + __expf(-g)) * u;
          __bf16 b = (__bf16)a;
          act[(size_t)slot * I_ + col] = *(ushort_t*)&b;
        }
      }
}

// ---------------------------------------------------------------- GEMM2
// partial[slot, h] = (act[slot,:] . w2s[e][h,:]) * slot_weight, bf16 out.
__global__ __launch_bounds__(256, 2) void k_gemm2(
    const ushort_t* __restrict__ act, const float* __restrict__ w2s,
    const float* __restrict__ slot_weight, const int* __restrict__ offsets,
    ushort_t* __restrict__ partial) {
  int e = blockIdx.z;
  int start = offsets[e], end = offsets[e + 1];
  int m0 = start + blockIdx.x * 128;
  if (m0 >= end) return;
  int n0 = blockIdx.y * 128;  // over H

  __shared__ ushort_t lA[128 * BK];
  __shared__ ushort_t lB[128 * BKP];

  int tid = threadIdx.x, lane = tid & 63, wv = tid >> 6;
  int wi = wv >> 1, wj = wv & 1;
  int q = lane >> 4, r16 = lane & 15;

  const ushort_t* aptr[2];
  ushort_t* adst[2];
#pragma unroll
  for (int j = 0; j < 2; ++j) {
    int row = wv * 32 + j * 16 + (lane >> 2);
    int slot = m0 + row;
    if (slot > end - 1) slot = end - 1;
    aptr[j] = act + (size_t)slot * I_ + (lane & 3) * 8;
    adst[j] = &lA[(wv * 32 + j * 16) * BK];
  }

  const float* bp[4];
  int boff[4];
  const float* wE = w2s + (size_t)e * H_ * (size_t)I_;
#pragma unroll
  for (int p = 0; p < 4; ++p) {
    int idx = p * 256 + tid;
    int row = idx >> 3, c4 = idx & 7;
    bp[p] = wE + (size_t)(n0 + row) * I_ + c4 * 4;
    boff[p] = row * BKP + c4 * 4;
  }

  f32x4 acc[4][4];
  f32x4 z4 = {0.f, 0.f, 0.f, 0.f};
#pragma unroll
  for (int a = 0; a < 4; ++a)
#pragma unroll
    for (int b = 0; b < 4; ++b) acc[a][b] = z4;

  for (int k0 = 0; k0 < I_; k0 += BK) {
#pragma unroll
    for (int j = 0; j < 2; ++j) gld_lds16(aptr[j] + k0, adst[j]);
#pragma unroll
    for (int p = 0; p < 4; ++p) {
      float4 v = *(const float4*)(bp[p] + k0);
      bf16x4 vb = {(__bf16)v.x, (__bf16)v.y, (__bf16)v.z, (__bf16)v.w};
      *(bf16x4*)&lB[boff[p]] = vb;
    }
    __syncthreads();
    short8 af[4], bf[4];
#pragma unroll
    for (int ti = 0; ti < 4; ++ti)
      af[ti] = *(const short8*)&lA[(wi * 64 + ti * 16 + r16) * BK + q * 8];
#pragma unroll
    for (int tj = 0; tj < 4; ++tj)
      bf[tj] = *(const short8*)&lB[(wj * 64 + tj * 16 + r16) * BKP + q * 8];
#pragma unroll
    for (int ti = 0; ti < 4; ++ti)
#pragma unroll
      for (int tj = 0; tj < 4; ++tj)
        acc[ti][tj] = __builtin_amdgcn_mfma_f32_16x16x32_bf16(
            af[ti], bf[tj], acc[ti][tj], 0, 0, 0);
    __syncthreads();
  }

#pragma unroll
  for (int ti = 0; ti < 4; ++ti)
#pragma unroll
    for (int r = 0; r < 4; ++r) {
      int mrow = wi * 64 + ti * 16 + q * 4 + r;
      int slot = m0 + mrow;
      if (slot < end) {
        float w = slot_weight[slot];
#pragma unroll
        for (int tj = 0; tj < 4; ++tj) {
          int col = n0 + wj * 64 + tj * 16 + r16;
          float v = acc[ti][tj][r] * w;
          __bf16 b = (__bf16)v;
          partial[(size_t)slot * H_ + col] = *(ushort_t*)&b;
        }
      }
    }
}

// ---------------------------------------------------------------- combine
__global__ __launch_bounds__(256) void k_combine(const ushort_t* __restrict__ partial,
                                                 const int* __restrict__ token_slots,
                                                 float* __restrict__ out) {
  int t = blockIdx.x;  // one block per token, 256 threads x 8 elems = 2048
  int tid = threadIdx.x;
  int s0 = token_slots[2 * t], s1 = token_slots[2 * t + 1];
  uint4 a = ((const uint4*)(partial + (size_t)s0 * H_))[tid];
  uint4 b = ((const uint4*)(partial + (size_t)s1 * H_))[tid];
#define BLO(u) __uint_as_float((u) << 16)
#define BHI(u) __uint_as_float((u) & 0xffff0000u)
  float4 o1, o2;
  o1.x = BLO(a.x) + BLO(b.x);
  o1.y = BHI(a.x) + BHI(b.x);
  o1.z = BLO(a.y) + BLO(b.y);
  o1.w = BHI(a.y) + BHI(b.y);
  o2.x = BLO(a.z) + BLO(b.z);
  o2.y = BHI(a.z) + BHI(b.z);
  o2.z = BLO(a.w) + BLO(b.w);
  o2.w = BHI(a.w) + BHI(b.w);
#undef BLO
#undef BHI
  float4* orow = (float4*)(out + (size_t)t * H_);
  orow[2 * tid] = o1;
  orow[2 * tid + 1] = o2;
}

// ---------------------------------------------------------------- launch
extern "C" void kernel_launch(void* const* d_in, const int* in_sizes, int n_in,
                              void* d_out, int out_size, void* d_ws, size_t ws_size,
                              hipStream_t stream) {
  const float* hidden = (const float*)d_in[0];
  const float* rw = (const float*)d_in[1];
  const float* ws_w = (const float*)d_in[2];
  const float* w2s = (const float*)d_in[3];
  float* out = (float*)d_out;

  char* W = (char*)d_ws;
  size_t off = 0;
  ushort_t* hidden_bf = (ushort_t*)(W + off);
  off += (size_t)T_ * H_ * 2;  // 33.5 MB
  ushort_t* act = (ushort_t*)(W + off);
  off += (size_t)NSLOT * I_ * 2;  // 134 MB
  ushort_t* partial = (ushort_t*)(W + off);
  off += (size_t)NSLOT * H_ * 2;  // 67 MB
  int* bucket_token = (int*)(W + off);
  off += NSLOT * 4;
  float* slot_weight = (float*)(W + off);
  off += NSLOT * 4;
  int* token_slots = (int*)(W + off);
  off += NSLOT * 4;
  int* topi = (int*)(W + off);
  off += NSLOT * 4;
  float* topw = (float*)(W + off);
  off += NSLOT * 4;
  int* ctrl = (int*)(W + off);  // counts[8] | cursors[8] | offsets[9]
  int* counts = ctrl;
  int* cursors = ctrl + 8;
  int* offsets = ctrl + 16;

  hipMemsetAsync(ctrl, 0, 25 * sizeof(int), stream);
  k_convert<<<(T_ * H_ / 4) / 256, 256, 0, stream>>>(hidden, hidden_bf);
  k_router<<<T_ / 4, 256, 0, stream>>>(hidden, rw, topi, topw, counts);
  k_prefix<<<1, 64, 0, stream>>>(counts, offsets);
  k_scatter<<<T_ / 256, 256, 0, stream>>>(topi, topw, offsets, cursors,
                                          bucket_token, slot_weight, token_slots);
  // Grid: x = M-tiles (fastest-varying -> concurrent blocks share B strips)
  k_gemm1<<<dim3(T_ / 128, I_ / 128, E_), 256, 0, stream>>>(
      hidden_bf, ws_w, bucket_token, offsets, act);
  k_gemm2<<<dim3(T_ / 128, H_ / 128, E_), 256, 0, stream>>>(
      act, w2s, slot_weight, offsets, partial);
  k_combine<<<T_, 256, 0, stream>>>(partial, token_slots, out);
}

// Round 2
// 3084.652 us; speedup vs baseline: 1.1266x; 1.1266x over previous
//
#include <hip/hip_runtime.h>
#include <hip/hip_bf16.h>
#include <stdint.h>

// Mixtral MoE MLP: T=8192, H=2048, I=4096, E=8, top-2.
// R2: pre-convert fp32 weights -> bf16 workspace, both GEMMs use the
// m97 structure (global_load_lds width=16 for A and B, bf16 MFMA 16x16x32,
// 128x128 tiles, BK=32). Fallback to R1 inline-cvt kernels if ws too small.

#define T_ 8192
#define H_ 2048
#define I_ 4096
#define E_ 8
#define NSLOT (T_ * 2)

#define BK 32
#define BKP 40  // padded LDS row for the fallback VALU-staged B tiles

typedef unsigned short ushort_t;
typedef __attribute__((ext_vector_type(8))) short short8;
typedef __attribute__((ext_vector_type(4))) float f32x4;
typedef __attribute__((ext_vector_type(4))) __bf16 bf16x4;

// ---------------------------------------------------------------- convert
__global__ __launch_bounds__(256) void k_convert(const float* __restrict__ src,
                                                 ushort_t* __restrict__ dst) {
  int idx = blockIdx.x * 256 + threadIdx.x;  // one float4 per thread
  float4 v = ((const float4*)src)[idx];
  bf16x4 b = {(__bf16)v.x, (__bf16)v.y, (__bf16)v.z, (__bf16)v.w};
  ((bf16x4*)dst)[idx] = b;
}

// ---------------------------------------------------------------- router
__global__ __launch_bounds__(256) void k_router(const float* __restrict__ hidden,
                                                const float* __restrict__ rw,
                                                int* __restrict__ topi,
                                                float* __restrict__ topw,
                                                int* __restrict__ counts) {
  int wv = threadIdx.x >> 6, lane = threadIdx.x & 63;
  int t = blockIdx.x * 4 + wv;  // one wave per token
  float acc[E_];
#pragma unroll
  for (int e = 0; e < E_; ++e) acc[e] = 0.f;
  const float* hrow = hidden + (size_t)t * H_;
  for (int j = lane; j < H_; j += 64) {
    float h = hrow[j];
#pragma unroll
    for (int e = 0; e < E_; ++e) acc[e] += h * rw[e * H_ + j];
  }
#pragma unroll
  for (int e = 0; e < E_; ++e) {
    float v = acc[e];
    for (int off = 32; off; off >>= 1) v += __shfl_xor(v, off, 64);
    acc[e] = v;
  }
  if (lane == 0) {
    int i0 = 0;
#pragma unroll
    for (int e = 1; e < E_; ++e)
      if (acc[e] > acc[i0]) i0 = e;
    int i1 = -1;
#pragma unroll
    for (int e = 0; e < E_; ++e) {
      if (e == i0) continue;
      if (i1 < 0 || acc[e] > acc[i1]) i1 = e;
    }
    float w0 = 1.f / (1.f + __expf(acc[i1] - acc[i0]));
    topi[2 * t] = i0;
    topi[2 * t + 1] = i1;
    topw[2 * t] = w0;
    topw[2 * t + 1] = 1.f - w0;
    atomicAdd(&counts[i0], 1);
    atomicAdd(&counts[i1], 1);
  }
}

// ---------------------------------------------------------------- prefix
__global__ void k_prefix(const int* __restrict__ counts, int* __restrict__ offsets) {
  if (threadIdx.x == 0 && blockIdx.x == 0) {
    int s = 0;
    for (int e = 0; e < E_; ++e) {
      offsets[e] = s;
      s += counts[e];
    }
    offsets[E_] = s;
  }
}

// ---------------------------------------------------------------- scatter
__global__ __launch_bounds__(256) void k_scatter(const int* __restrict__ topi,
                                                 const float* __restrict__ topw,
                                                 const int* __restrict__ offsets,
                                                 int* __restrict__ cursors,
                                                 int* __restrict__ bucket_token,
                                                 float* __restrict__ slot_weight,
                                                 int* __restrict__ token_slots) {
  int t = blockIdx.x * 256 + threadIdx.x;
  if (t >= T_) return;
#pragma unroll
  for (int k = 0; k < 2; ++k) {
    int e = topi[2 * t + k];
    int pos = atomicAdd(&cursors[e], 1);
    int slot = offsets[e] + pos;
    bucket_token[slot] = t;
    slot_weight[slot] = topw[2 * t + k];
    token_slots[2 * t + k] = slot;
  }
}

// ------------------------------------------------------- async global->LDS
__device__ __forceinline__ void gld_lds16(const void* g, void* l) {
  __builtin_amdgcn_global_load_lds(
      (const __attribute__((address_space(1))) unsigned int*)g,
      (__attribute__((address_space(3))) unsigned int*)l, 16, 0, 0);
}

// ================================================================= Plan A
// GEMM1 (bf16 B): act[slot,i] = silu(h.g_i) * (h.u_i). Grid (Mtile, I/128, E)
__global__ __launch_bounds__(256, 2) void k_gemm1b(
    const ushort_t* __restrict__ hidden_bf, const ushort_t* __restrict__ ws_bf,
    const int* __restrict__ bucket_token, const int* __restrict__ offsets,
    ushort_t* __restrict__ act) {
  int e = blockIdx.z;
  int start = offsets[e], end = offsets[e + 1];
  int m0 = start + blockIdx.x * 128;
  if (m0 >= end) return;
  int i0 = blockIdx.y * 128;

  __shared__ ushort_t lA[128 * BK];   // 8 KB
  __shared__ ushort_t lBg[128 * BK];  // 8 KB
  __shared__ ushort_t lBu[128 * BK];  // 8 KB

  int tid = threadIdx.x, lane = tid & 63, wv = tid >> 6;
  int wi = wv >> 1, wj = wv & 1;  // 2x2 waves, 64x64 each
  int q = lane >> 4, r16 = lane & 15;

  // A staging (gathered rows): wave wv covers rows [wv*32, +32), 2 instrs
  const ushort_t* aptr[2];
  ushort_t* adst[2];
#pragma unroll
  for (int j = 0; j < 2; ++j) {
    int row = wv * 32 + j * 16 + (lane >> 2);
    int slot = m0 + row;
    if (slot > end - 1) slot = end - 1;  // tail clamp (epilogue masks)
    int tok = bucket_token[slot];
    aptr[j] = hidden_bf + (size_t)tok * H_ + (lane & 3) * 8;
    adst[j] = &lA[(wv * 32 + j * 16) * BK];
  }
  // B staging: wave wv covers gate rows [wv*32,+32) and up rows, 2+2 instrs
  const ushort_t* bgp[2];
  const ushort_t* bup[2];
  ushort_t* bgd[2];
  ushort_t* bud[2];
  const ushort_t* wsE = ws_bf + (size_t)e * (2 * I_) * (size_t)H_;
#pragma unroll
  for (int j = 0; j < 2; ++j) {
    int row = wv * 32 + j * 16 + (lane >> 2);
    bgp[j] = wsE + (size_t)(i0 + row) * H_ + (lane & 3) * 8;
    bup[j] = wsE + (size_t)(I_ + i0 + row) * H_ + (lane & 3) * 8;
    bgd[j] = &lBg[(wv * 32 + j * 16) * BK];
    bud[j] = &lBu[(wv * 32 + j * 16) * BK];
  }

  f32x4 accg[4][4], accu[4][4];
  f32x4 z4 = {0.f, 0.f, 0.f, 0.f};
#pragma unroll
  for (int a = 0; a < 4; ++a)
#pragma unroll
    for (int b = 0; b < 4; ++b) {
      accg[a][b] = z4;
      accu[a][b] = z4;
    }

  for (int k0 = 0; k0 < H_; k0 += BK) {
#pragma unroll
    for (int j = 0; j < 2; ++j) {
      gld_lds16(aptr[j] + k0, adst[j]);
      gld_lds16(bgp[j] + k0, bgd[j]);
      gld_lds16(bup[j] + k0, bud[j]);
    }
    __syncthreads();
    short8 af[4], bg[4], bu2[4];
#pragma unroll
    for (int ti = 0; ti < 4; ++ti)
      af[ti] = *(const short8*)&lA[(wi * 64 + ti * 16 + r16) * BK + q * 8];
#pragma unroll
    for (int tj = 0; tj < 4; ++tj) {
      bg[tj] = *(const short8*)&lBg[(wj * 64 + tj * 16 + r16) * BK + q * 8];
      bu2[tj] = *(const short8*)&lBu[(wj * 64 + tj * 16 + r16) * BK + q * 8];
    }
#pragma unroll
    for (int ti = 0; ti < 4; ++ti)
#pragma unroll
      for (int tj = 0; tj < 4; ++tj) {
        accg[ti][tj] = __builtin_amdgcn_mfma_f32_16x16x32_bf16(
            af[ti], bg[tj], accg[ti][tj], 0, 0, 0);
        accu[ti][tj] = __builtin_amdgcn_mfma_f32_16x16x32_bf16(
            af[ti], bu2[tj], accu[ti][tj], 0, 0, 0);
      }
    __syncthreads();
  }

#pragma unroll
  for (int ti = 0; ti < 4; ++ti)
#pragma unroll
    for (int tj = 0; tj < 4; ++tj)
#pragma unroll
      for (int r = 0; r < 4; ++r) {
        int mrow = wi * 64 + ti * 16 + q * 4 + r;
        int slot = m0 + mrow;
        if (slot < end) {
          int col = i0 + wj * 64 + tj * 16 + r16;
          float g = accg[ti][tj][r], u = accu[ti][tj][r];
          float a = g / (1.f + __expf(-g)) * u;
          __bf16 b = (__bf16)a;
          act[(size_t)slot * I_ + col] = *(ushort_t*)&b;
        }
      }
}

// GEMM2 (bf16 B): partial[slot,h] = (act[slot,:].w2[h,:]) * slot_weight
__global__ __launch_bounds__(256, 2) void k_gemm2b(
    const ushort_t* __restrict__ act, const ushort_t* __restrict__ w2_bf,
    const float* __restrict__ slot_weight, const int* __restrict__ offsets,
    ushort_t* __restrict__ partial) {
  int e = blockIdx.z;
  int start = offsets[e], end = offsets[e + 1];
  int m0 = start + blockIdx.x * 128;
  if (m0 >= end) return;
  int n0 = blockIdx.y * 128;

  __shared__ ushort_t lA[128 * BK];
  __shared__ ushort_t lB[128 * BK];

  int tid = threadIdx.x, lane = tid & 63, wv = tid >> 6;
  int wi = wv >> 1, wj = wv & 1;
  int q = lane >> 4, r16 = lane & 15;

  const ushort_t* aptr[2];
  ushort_t* adst[2];
#pragma unroll
  for (int j = 0; j < 2; ++j) {
    int row = wv * 32 + j * 16 + (lane >> 2);
    int slot = m0 + row;
    if (slot > end - 1) slot = end - 1;
    aptr[j] = act + (size_t)slot * I_ + (lane & 3) * 8;
    adst[j] = &lA[(wv * 32 + j * 16) * BK];
  }
  const ushort_t* bp[2];
  ushort_t* bd[2];
  const ushort_t* wE = w2_bf + (size_t)e * H_ * (size_t)I_;
#pragma unroll
  for (int j = 0; j < 2; ++j) {
    int row = wv * 32 + j * 16 + (lane >> 2);
    bp[j] = wE + (size_t)(n0 + row) * I_ + (lane & 3) * 8;
    bd[j] = &lB[(wv * 32 + j * 16) * BK];
  }

  f32x4 acc[4][4];
  f32x4 z4 = {0.f, 0.f, 0.f, 0.f};
#pragma unroll
  for (int a = 0; a < 4; ++a)
#pragma unroll
    for (int b = 0; b < 4; ++b) acc[a][b] = z4;

  for (int k0 = 0; k0 < I_; k0 += BK) {
#pragma unroll
    for (int j = 0; j < 2; ++j) {
      gld_lds16(aptr[j] + k0, adst[j]);
      gld_lds16(bp[j] + k0, bd[j]);
    }
    __syncthreads();
    short8 af[4], bf[4];
#pragma unroll
    for (int ti = 0; ti < 4; ++ti)
      af[ti] = *(const short8*)&lA[(wi * 64 + ti * 16 + r16) * BK + q * 8];
#pragma unroll
    for (int tj = 0; tj < 4; ++tj)
      bf[tj] = *(const short8*)&lB[(wj * 64 + tj * 16 + r16) * BK + q * 8];
#pragma unroll
    for (int ti = 0; ti < 4; ++ti)
#pragma unroll
      for (int tj = 0; tj < 4; ++tj)
        acc[ti][tj] = __builtin_amdgcn_mfma_f32_16x16x32_bf16(
            af[ti], bf[tj], acc[ti][tj], 0, 0, 0);
    __syncthreads();
  }

#pragma unroll
  for (int ti = 0; ti < 4; ++ti)
#pragma unroll
    for (int r = 0; r < 4; ++r) {
      int mrow = wi * 64 + ti * 16 + q * 4 + r;
      int slot = m0 + mrow;
      if (slot < end) {
        float w = slot_weight[slot];
#pragma unroll
        for (int tj = 0; tj < 4; ++tj) {
          int col = n0 + wj * 64 + tj * 16 + r16;
          float v = acc[ti][tj][r] * w;
          __bf16 b = (__bf16)v;
          partial[(size_t)slot * H_ + col] = *(ushort_t*)&b;
        }
      }
    }
}

// ============================================================== fallback
// R1 inline-cvt GEMMs (used only if ws_size < Plan A footprint)
__global__ __launch_bounds__(256, 2) void k_gemm1_f32(
    const ushort_t* __restrict__ hidden_bf, const float* __restrict__ ws,
    const int* __restrict__ bucket_token, const int* __restrict__ offsets,
    ushort_t* __restrict__ act) {
  int e = blockIdx.z;
  int start = offsets[e], end = offsets[e + 1];
  int m0 = start + blockIdx.x * 128;
  if (m0 >= end) return;
  int i0 = blockIdx.y * 128;
  __shared__ ushort_t lA[128 * BK];
  __shared__ ushort_t lBg[128 * BKP];
  __shared__ ushort_t lBu[128 * BKP];
  int tid = threadIdx.x, lane = tid & 63, wv = tid >> 6;
  int wi = wv >> 1, wj = wv & 1;
  int q = lane >> 4, r16 = lane & 15;
  const ushort_t* aptr[2];
  ushort_t* adst[2];
#pragma unroll
  for (int j = 0; j < 2; ++j) {
    int row = wv * 32 + j * 16 + (lane >> 2);
    int slot = m0 + row;
    if (slot > end - 1) slot = end - 1;
    int tok = bucket_token[slot];
    aptr[j] = hidden_bf + (size_t)tok * H_ + (lane & 3) * 8;
    adst[j] = &lA[(wv * 32 + j * 16) * BK];
  }
  const float* bgp[4];
  const float* bup[4];
  int boff[4];
  const float* wsE = ws + (size_t)e * (2 * I_) * (size_t)H_;
#pragma unroll
  for (int p = 0; p < 4; ++p) {
    int idx = p * 256 + tid;
    int row = idx >> 3, c4 = idx & 7;
    bgp[p] = wsE + (size_t)(i0 + row) * H_ + c4 * 4;
    bup[p] = wsE + (size_t)(I_ + i0 + row) * H_ + c4 * 4;
    boff[p] = row * BKP + c4 * 4;
  }
  f32x4 accg[4][4], accu[4][4];
  f32x4 z4 = {0.f, 0.f, 0.f, 0.f};
#pragma unroll
  for (int a = 0; a < 4; ++a)
#pragma unroll
    for (int b = 0; b < 4; ++b) {
      accg[a][b] = z4;
      accu[a][b] = z4;
    }
  for (int k0 = 0; k0 < H_; k0 += BK) {
#pragma unroll
    for (int j = 0; j < 2; ++j) gld_lds16(aptr[j] + k0, adst[j]);
#pragma unroll
    for (int p = 0; p < 4; ++p) {
      float4 g = *(const float4*)(bgp[p] + k0);
      float4 u = *(const float4*)(bup[p] + k0);
      bf16x4 gb = {(__bf16)g.x, (__bf16)g.y, (__bf16)g.z, (__bf16)g.w};
      bf16x4 ub = {(__bf16)u.x, (__bf16)u.y, (__bf16)u.z, (__bf16)u.w};
      *(bf16x4*)&lBg[boff[p]] = gb;
      *(bf16x4*)&lBu[boff[p]] = ub;
    }
    __syncthreads();
    short8 af[4], bg[4], bu2[4];
#pragma unroll
    for (int ti = 0; ti < 4; ++ti)
      af[ti] = *(const short8*)&lA[(wi * 64 + ti * 16 + r16) * BK + q * 8];
#pragma unroll
    for (int tj = 0; tj < 4; ++tj) {
      bg[tj] = *(const short8*)&lBg[(wj * 64 + tj * 16 + r16) * BKP + q * 8];
      bu2[tj] = *(const short8*)&lBu[(wj * 64 + tj * 16 + r16) * BKP + q * 8];
    }
#pragma unroll
    for (int ti = 0; ti < 4; ++ti)
#pragma unroll
      for (int tj = 0; tj < 4; ++tj) {
        accg[ti][tj] = __builtin_amdgcn_mfma_f32_16x16x32_bf16(
            af[ti], bg[tj], accg[ti][tj], 0, 0, 0);
        accu[ti][tj] = __builtin_amdgcn_mfma_f32_16x16x32_bf16(
            af[ti], bu2[tj], accu[ti][tj], 0, 0, 0);
      }
    __syncthreads();
  }
#pragma unroll
  for (int ti = 0; ti < 4; ++ti)
#pragma unroll
    for (int tj = 0; tj < 4; ++tj)
#pragma unroll
      for (int r = 0; r < 4; ++r) {
        int mrow = wi * 64 + ti * 16 + q * 4 + r;
        int slot = m0 + mrow;
        if (slot < end) {
          int col = i0 + wj * 64 + tj * 16 + r16;
          float g = accg[ti][tj][r], u = accu[ti][tj][r];
          float a = g / (1.f + __expf(-g)) * u;
          __bf16 b = (__bf16)a;
          act[(size_t)slot * I_ + col] = *(ushort_t*)&b;
        }
      }
}

__global__ __launch_bounds__(256, 2) void k_gemm2_f32(
    const ushort_t* __restrict__ act, const float* __restrict__ w2s,
    const float* __restrict__ slot_weight, const int* __restrict__ offsets,
    ushort_t* __restrict__ partial) {
  int e = blockIdx.z;
  int start = offsets[e], end = offsets[e + 1];
  int m0 = start + blockIdx.x * 128;
  if (m0 >= end) return;
  int n0 = blockIdx.y * 128;
  __shared__ ushort_t lA[128 * BK];
  __shared__ ushort_t lB[128 * BKP];
  int tid = threadIdx.x, lane = tid & 63, wv = tid >> 6;
  int wi = wv >> 1, wj = wv & 1;
  int q = lane >> 4, r16 = lane & 15;
  const ushort_t* aptr[2];
  ushort_t* adst[2];
#pragma unroll
  for (int j = 0; j < 2; ++j) {
    int row = wv * 32 + j * 16 + (lane >> 2);
    int slot = m0 + row;
    if (slot > end - 1) slot = end - 1;
    aptr[j] = act + (size_t)slot * I_ + (lane & 3) * 8;
    adst[j] = &lA[(wv * 32 + j * 16) * BK];
  }
  const float* bp[4];
  int boff[4];
  const float* wE = w2s + (size_t)e * H_ * (size_t)I_;
#pragma unroll
  for (int p = 0; p < 4; ++p) {
    int idx = p * 256 + tid;
    int row = idx >> 3, c4 = idx & 7;
    bp[p] = wE + (size_t)(n0 + row) * I_ + c4 * 4;
    boff[p] = row * BKP + c4 * 4;
  }
  f32x4 acc[4][4];
  f32x4 z4 = {0.f, 0.f, 0.f, 0.f};
#pragma unroll
  for (int a = 0; a < 4; ++a)
#pragma unroll
    for (int b = 0; b < 4; ++b) acc[a][b] = z4;
  for (int k0 = 0; k0 < I_; k0 += BK) {
#pragma unroll
    for (int j = 0; j < 2; ++j) gld_lds16(aptr[j] + k0, adst[j]);
#pragma unroll
    for (int p = 0; p < 4; ++p) {
      float4 v = *(const float4*)(bp[p] + k0);
      bf16x4 vb = {(__bf16)v.x, (__bf16)v.y, (__bf16)v.z, (__bf16)v.w};
      *(bf16x4*)&lB[boff[p]] = vb;
    }
    __syncthreads();
    short8 af[4], bf[4];
#pragma unroll
    for (int ti = 0; ti < 4; ++ti)
      af[ti] = *(const short8*)&lA[(wi * 64 + ti * 16 + r16) * BK + q * 8];
#pragma unroll
    for (int tj = 0; tj < 4; ++tj)
      bf[tj] = *(const short8*)&lB[(wj * 64 + tj * 16 + r16) * BKP + q * 8];
#pragma unroll
    for (int ti = 0; ti < 4; ++ti)
#pragma unroll
      for (int tj = 0; tj < 4; ++tj)
        acc[ti][tj] = __builtin_amdgcn_mfma_f32_16x16x32_bf16(
            af[ti], bf[tj], acc[ti][tj], 0, 0, 0);
    __syncthreads();
  }
#pragma unroll
  for (int ti = 0; ti < 4; ++ti)
#pragma unroll
    for (int r = 0; r < 4; ++r) {
      int mrow = wi * 64 + ti * 16 + q * 4 + r;
      int slot = m0 + mrow;
      if (slot < end) {
        float w = slot_weight[slot];
#pragma unroll
        for (int tj = 0; tj < 4; ++tj) {
          int col = n0 + wj * 64 + tj * 16 + r16;
          float v = acc[ti][tj][r] * w;
          __bf16 b = (__bf16)v;
          partial[(size_t)slot * H_ + col] = *(ushort_t*)&b;
        }
      }
    }
}

// ---------------------------------------------------------------- combine
__global__ __launch_bounds__(256) void k_combine(const ushort_t* __restrict__ partial,
                                                 const int* __restrict__ token_slots,
                                                 float* __restrict__ out) {
  int t = blockIdx.x;
  int tid = threadIdx.x;
  int s0 = token_slots[2 * t], s1 = token_slots[2 * t + 1];
  uint4 a = ((const uint4*)(partial + (size_t)s0 * H_))[tid];
  uint4 b = ((const uint4*)(partial + (size_t)s1 * H_))[tid];
#define BLO(u) __uint_as_float((u) << 16)
#define BHI(u) __uint_as_float((u) & 0xffff0000u)
  float4 o1, o2;
  o1.x = BLO(a.x) + BLO(b.x);
  o1.y = BHI(a.x) + BHI(b.x);
  o1.z = BLO(a.y) + BLO(b.y);
  o1.w = BHI(a.y) + BHI(b.y);
  o2.x = BLO(a.z) + BLO(b.z);
  o2.y = BHI(a.z) + BHI(b.z);
  o2.z = BLO(a.w) + BLO(b.w);
  o2.w = BHI(a.w) + BHI(b.w);
#undef BLO
#undef BHI
  float4* orow = (float4*)(out + (size_t)t * H_);
  orow[2 * tid] = o1;
  orow[2 * tid + 1] = o2;
}

// ---------------------------------------------------------------- launch
extern "C" void kernel_launch(void* const* d_in, const int* in_sizes, int n_in,
                              void* d_out, int out_size, void* d_ws, size_t ws_size,
                              hipStream_t stream) {
  const float* hidden = (const float*)d_in[0];
  const float* rw = (const float*)d_in[1];
  const float* ws_w = (const float*)d_in[2];
  const float* w2s = (const float*)d_in[3];
  float* out = (float*)d_out;

  const size_t SZ_HID = (size_t)T_ * H_ * 2;          // 33.5 MB
  const size_t SZ_WSX = (size_t)E_ * 2 * I_ * H_ * 2; // 268.4 MB (>= w2s_bf 134 MB)
  const size_t SZ_ACT = (size_t)NSLOT * I_ * 2;       // 134.2 MB
  const size_t SZ_PAR = (size_t)NSLOT * H_ * 2;       // 67.1 MB
  const size_t SZ_MISC = (size_t)NSLOT * 4 * 5 + 256;
  const size_t NEED_A = SZ_HID + SZ_WSX + SZ_ACT + SZ_PAR + SZ_MISC;

  char* W = (char*)d_ws;
  if (ws_size >= NEED_A) {
    // ----- Plan A: pre-converted bf16 weights, m97-structure GEMMs -----
    size_t off = 0;
    ushort_t* hidden_bf = (ushort_t*)(W + off); off += SZ_HID;
    ushort_t* wsX = (ushort_t*)(W + off); off += SZ_WSX;  // ws_bf, later w2s_bf
    ushort_t* act = (ushort_t*)(W + off); off += SZ_ACT;
    ushort_t* partial = (ushort_t*)(W + off); off += SZ_PAR;
    int* bucket_token = (int*)(W + off); off += NSLOT * 4;
    float* slot_weight = (float*)(W + off); off += NSLOT * 4;
    int* token_slots = (int*)(W + off); off += NSLOT * 4;
    int* topi = (int*)(W + off); off += NSLOT * 4;
    float* topw = (float*)(W + off); off += NSLOT * 4;
    int* ctrl = (int*)(W + off);
    int* counts = ctrl;
    int* cursors = ctrl + 8;
    int* offsets = ctrl + 16;

    hipMemsetAsync(ctrl, 0, 25 * sizeof(int), stream);
    k_convert<<<(T_ * H_ / 4) / 256, 256, 0, stream>>>(hidden, hidden_bf);
    k_router<<<T_ / 4, 256, 0, stream>>>(hidden, rw, topi, topw, counts);
    k_prefix<<<1, 64, 0, stream>>>(counts, offsets);
    k_scatter<<<T_ / 256, 256, 0, stream>>>(topi, topw, offsets, cursors,
                                            bucket_token, slot_weight, token_slots);
    // convert ws (fp32 -> bf16): E*2I*H = 134.2e6 elems
    k_convert<<<(E_ * 2 * I_ * H_ / 4) / 256, 256, 0, stream>>>(ws_w, wsX);
    k_gemm1b<<<dim3(T_ / 128, I_ / 128, E_), 256, 0, stream>>>(
        hidden_bf, wsX, bucket_token, offsets, act);
    // ws_bf no longer needed -> reuse region for w2s_bf (E*H*I elems)
    k_convert<<<(E_ * H_ * I_ / 4) / 256, 256, 0, stream>>>(w2s, wsX);
    k_gemm2b<<<dim3(T_ / 128, H_ / 128, E_), 256, 0, stream>>>(
        act, wsX, slot_weight, offsets, partial);
    k_combine<<<T_, 256, 0, stream>>>(partial, token_slots, out);
  } else {
    // ----- Fallback: R1 inline-convert path (~235 MB) -----
    size_t off = 0;
    ushort_t* hidden_bf = (ushort_t*)(W + off); off += SZ_HID;
    ushort_t* act = (ushort_t*)(W + off); off += SZ_ACT;
    ushort_t* partial = (ushort_t*)(W + off); off += SZ_PAR;
    int* bucket_token = (int*)(W + off); off += NSLOT * 4;
    float* slot_weight = (float*)(W + off); off += NSLOT * 4;
    int* token_slots = (int*)(W + off); off += NSLOT * 4;
    int* topi = (int*)(W + off); off += NSLOT * 4;
    float* topw = (float*)(W + off); off += NSLOT * 4;
    int* ctrl = (int*)(W + off);
    int* counts = ctrl;
    int* cursors = ctrl + 8;
    int* offsets = ctrl + 16;

    hipMemsetAsync(ctrl, 0, 25 * sizeof(int), stream);
    k_convert<<<(T_ * H_ / 4) / 256, 256, 0, stream>>>(hidden, hidden_bf);
    k_router<<<T_ / 4, 256, 0, stream>>>(hidden, rw, topi, topw, counts);
    k_prefix<<<1, 64, 0, stream>>>(counts, offsets);
    k_scatter<<<T_ / 256, 256, 0, stream>>>(topi, topw, offsets, cursors,
                                            bucket_token, slot_weight, token_slots);
    k_gemm1_f32<<<dim3(T_ / 128, I_ / 128, E_), 256, 0, stream>>>(
        hidden_bf, ws_w, bucket_token, offsets, act);
    k_gemm2_f32<<<dim3(T_ / 128, H_ / 128, E_), 256, 0, stream>>>(
        act, w2s, slot_weight, offsets, partial);
    k_combine<<<T_, 256, 0, stream>>>(partial, token_slots, out);
  }
}